// Round 9
// baseline (1463.611 us; speedup 1.0000x reference)
//
#include <hip/hip_runtime.h>

constexpr int NPIX = 196608;
constexpr int FF   = 32;
constexpr size_t SLOT = (size_t)NPIX * FF;

typedef short bf16x8 __attribute__((ext_vector_type(8)));
typedef float f32x4  __attribute__((ext_vector_type(4)));
typedef int   i32x4  __attribute__((ext_vector_type(4)));
typedef uint  u32x4  __attribute__((ext_vector_type(4)));

__device__ __forceinline__ float blo(uint u) {
    union { float f; uint i; } v; v.i = u << 16; return v.f;
}
__device__ __forceinline__ float bhi(uint u) {
    union { float f; uint i; } v; v.i = u & 0xffff0000u; return v.f;
}
__device__ __forceinline__ ushort f2b(float f) {
    union { float f; uint i; } v; v.f = f;
    uint r = v.i + 0x7fffu + ((v.i >> 16) & 1u);   // RNE
    return (ushort)(r >> 16);
}
__device__ __forceinline__ uint pack2(float lo, float hi) {
    return ((uint)f2b(hi) << 16) | (uint)f2b(lo);
}
__device__ __forceinline__ float wbits(ulong e) {
    union { float f; uint u; } v; v.u = (uint)e; return v.f;
}

// ---------------- fp32 -> bf16 convert (maps -> chain T0) ----------------
__global__ __launch_bounds__(256) void f2b_kernel(const float* __restrict__ src,
                                                  ushort* __restrict__ dst) {
    int i = (blockIdx.x * 256 + threadIdx.x) * 4;
    f32x4 v = *reinterpret_cast<const f32x4*>(src + i);
    ushort4 o;
    o.x = f2b(v.x); o.y = f2b(v.y); o.z = f2b(v.z); o.w = f2b(v.w);
    *reinterpret_cast<ushort4*>(dst + i) = o;
}

// ---- one-time: pack (idx,w) into ulong and sort each node's edges by src ----
template<int NB>
__global__ __launch_bounds__(256) void sort_edges(
    const int*   __restrict__ idx,
    const float* __restrict__ wnb,
    ulong*       __restrict__ edges)
{
    int n = blockIdx.x * 256 + threadIdx.x;
    ulong a[NB];
#pragma unroll
    for (int j = 0; j < NB; ++j) {
        union { float f; uint u; } w; w.f = wnb[(size_t)n * NB + j];
        a[j] = ((ulong)(uint)idx[(size_t)n * NB + j] << 32) | (ulong)w.u;
    }
#pragma unroll
    for (int r = 0; r < NB; ++r) {
#pragma unroll
        for (int i = (r & 1); i + 1 < NB; i += 2) {
            if (a[i] > a[i + 1]) { ulong t = a[i]; a[i] = a[i + 1]; a[i + 1] = t; }
        }
    }
#pragma unroll
    for (int j = 0; j < NB; ++j)
        edges[(size_t)n * NB + j] = a[j];
}

// ---- one-time: sorted edges -> 32 padded slots (8 buckets x cap 4) ----
// Slot assignment: s[j] = max(s[j-1]+1, 4*bucket(src_j)), clamped to 31 with a
// backward shift (overflow edges run EARLY -> still correct, mild cold miss).
// Empty slots: (w=0, src=last real src) -> L1-hit gather, FMA no-op.
template<int NB, int NSLOT>
__global__ __launch_bounds__(256) void build_slots(
    const int*   __restrict__ idx,
    const float* __restrict__ wnb,
    ulong*       __restrict__ edgesP)
{
    constexpr int NBUCK = NSLOT / 4;
    constexpr int BW = NPIX / NBUCK;
    int n = blockIdx.x * 256 + threadIdx.x;

    ulong a[NB];
#pragma unroll
    for (int j = 0; j < NB; ++j) {
        union { float f; uint u; } w; w.f = wnb[(size_t)n * NB + j];
        a[j] = ((ulong)(uint)idx[(size_t)n * NB + j] << 32) | (ulong)w.u;
    }
#pragma unroll
    for (int r = 0; r < NB; ++r) {
#pragma unroll
        for (int i = (r & 1); i + 1 < NB; i += 2) {
            if (a[i] > a[i + 1]) { ulong t = a[i]; a[i] = a[i + 1]; a[i + 1] = t; }
        }
    }

    int s[NB];
    int prev = -1;
#pragma unroll
    for (int j = 0; j < NB; ++j) {
        int src = (int)(a[j] >> 32);
        int b = src / BW;
        int want = b * 4;
        s[j] = (prev + 1 > want) ? prev + 1 : want;
        prev = s[j];
    }
    if (s[NB - 1] > NSLOT - 1) s[NB - 1] = NSLOT - 1;
#pragma unroll
    for (int j = NB - 2; j >= 0; --j)
        if (s[j] > s[j + 1] - 1) s[j] = s[j + 1] - 1;

    ulong* base = edgesP + (size_t)n * NSLOT;
#pragma unroll
    for (int t = 0; t < NSLOT; ++t)
        base[t] = 0xFFFFFFFF00000000ull;           // sentinel
#pragma unroll
    for (int j = 0; j < NB; ++j)
        base[s[j]] = a[j];
    uint lastSrc = (uint)(a[0] >> 32);
#pragma unroll
    for (int t = 0; t < NSLOT; ++t) {
        ulong e = base[t];
        if ((uint)(e >> 32) == 0xFFFFFFFFu) base[t] = ((ulong)lastSrc << 32);  // w=0
        else lastSrc = (uint)(e >> 32);
    }
}

// ---- padded-slot sweep: 8 chunks x 4 gathers, exact windows + ILP=4 ----
// INIT: Tout = L(Tprev). else: Tout = 2 L(Tprev) - Told.
template<int NSLOT, bool INIT>
__global__ __launch_bounds__(256, 4) void cheb_stepP(
    const ushort* __restrict__ Tprev,
    const ushort* __restrict__ Told,
    ushort*       __restrict__ Tout,
    const ulong*  __restrict__ edgesP)
{
    constexpr int NCH = NSLOT / 4;
    int t = blockIdx.x * 256 + threadIdx.x;
    int n = t >> 2;          // node
    int h = t & 3;           // feature octet

    const ulong2* ep = reinterpret_cast<const ulong2*>(edgesP + (size_t)n * NSLOT);
    const u32x4*  Tp = reinterpret_cast<const u32x4*>(Tprev);
    size_t base = (size_t)n * 4 + h;

    u32x4 told;
    if (!INIT) told = reinterpret_cast<const u32x4*>(Told)[base];

    float s0 = 0.f, s1 = 0.f, s2 = 0.f, s3 = 0.f;
    float s4 = 0.f, s5 = 0.f, s6 = 0.f, s7 = 0.f;

    ulong2 e01 = ep[0], e23 = ep[1];

#pragma unroll
    for (int c = 0; c < NCH; ++c) {
        ulong E0 = e01.x, E1 = e01.y, E2 = e23.x, E3 = e23.y;
        // 4 independent gathers for this window
        u32x4 u0 = Tp[(size_t)(uint)(E0 >> 32) * 4 + h];
        u32x4 u1 = Tp[(size_t)(uint)(E1 >> 32) * 4 + h];
        u32x4 u2 = Tp[(size_t)(uint)(E2 >> 32) * 4 + h];
        u32x4 u3 = Tp[(size_t)(uint)(E3 >> 32) * 4 + h];
        // issue next chunk's slot loads; they stay in flight across the barrier
        if (c + 1 < NCH) { e01 = ep[2 * (c + 1)]; e23 = ep[2 * (c + 1) + 1]; }
        float w0 = wbits(E0), w1 = wbits(E1), w2 = wbits(E2), w3 = wbits(E3);
        s0 += w0 * blo(u0.x); s1 += w0 * bhi(u0.x);
        s2 += w0 * blo(u0.y); s3 += w0 * bhi(u0.y);
        s4 += w0 * blo(u0.z); s5 += w0 * bhi(u0.z);
        s6 += w0 * blo(u0.w); s7 += w0 * bhi(u0.w);
        s0 += w1 * blo(u1.x); s1 += w1 * bhi(u1.x);
        s2 += w1 * blo(u1.y); s3 += w1 * bhi(u1.y);
        s4 += w1 * blo(u1.z); s5 += w1 * bhi(u1.z);
        s6 += w1 * blo(u1.w); s7 += w1 * bhi(u1.w);
        s0 += w2 * blo(u2.x); s1 += w2 * bhi(u2.x);
        s2 += w2 * blo(u2.y); s3 += w2 * bhi(u2.y);
        s4 += w2 * blo(u2.z); s5 += w2 * bhi(u2.z);
        s6 += w2 * blo(u2.w); s7 += w2 * bhi(u2.w);
        s0 += w3 * blo(u3.x); s1 += w3 * bhi(u3.x);
        s2 += w3 * blo(u3.y); s3 += w3 * bhi(u3.y);
        s4 += w3 * blo(u3.z); s5 += w3 * bhi(u3.z);
        s6 += w3 * blo(u3.w); s7 += w3 * bhi(u3.w);
        __builtin_amdgcn_sched_barrier(0);   // pin temporal sweep order
    }

    u32x4 o;
    if (INIT) {
        o.x = pack2(s0, s1); o.y = pack2(s2, s3);
        o.z = pack2(s4, s5); o.w = pack2(s6, s7);
    } else {
        o.x = pack2(2.f * s0 - blo(told.x), 2.f * s1 - bhi(told.x));
        o.y = pack2(2.f * s2 - blo(told.y), 2.f * s3 - bhi(told.y));
        o.z = pack2(2.f * s4 - blo(told.z), 2.f * s5 - bhi(told.z));
        o.w = pack2(2.f * s6 - blo(told.w), 2.f * s7 - bhi(told.w));
    }
    reinterpret_cast<u32x4*>(Tout)[base] = o;
}

// ---- layer-1 step (R8 form): chunked sorted sweep, NB=8, 2 chunks of 4 ----
template<int NB, int NCH, bool INIT>
__global__ __launch_bounds__(256, 4) void cheb_stepC(
    const ushort* __restrict__ Tprev,
    const ushort* __restrict__ Told,
    ushort*       __restrict__ Tout,
    const ulong*  __restrict__ edges)
{
    constexpr int CH = NB / NCH;
    int t = blockIdx.x * 256 + threadIdx.x;
    int n = t >> 2;
    int h = t & 3;

    ulong E[NB];
    const ulong* ep = edges + (size_t)n * NB;
#pragma unroll
    for (int j = 0; j < NB; ++j) E[j] = ep[j];

    const u32x4* Tp = reinterpret_cast<const u32x4*>(Tprev);
    float s0 = 0.f, s1 = 0.f, s2 = 0.f, s3 = 0.f;
    float s4 = 0.f, s5 = 0.f, s6 = 0.f, s7 = 0.f;

#pragma unroll
    for (int c = 0; c < NCH; ++c) {
        u32x4 u[CH];
        float w[CH];
#pragma unroll
        for (int i = 0; i < CH; ++i) {
            ulong e = E[c * CH + i];
            w[i] = wbits(e);
            u[i] = Tp[(size_t)(uint)(e >> 32) * 4 + h];
        }
#pragma unroll
        for (int i = 0; i < CH; ++i) {
            s0 += w[i] * blo(u[i].x); s1 += w[i] * bhi(u[i].x);
            s2 += w[i] * blo(u[i].y); s3 += w[i] * bhi(u[i].y);
            s4 += w[i] * blo(u[i].z); s5 += w[i] * bhi(u[i].z);
            s6 += w[i] * blo(u[i].w); s7 += w[i] * bhi(u[i].w);
        }
        __builtin_amdgcn_sched_barrier(0);
    }

    size_t base = (size_t)n * 4 + h;
    u32x4 o;
    if (INIT) {
        o.x = pack2(s0, s1); o.y = pack2(s2, s3);
        o.z = pack2(s4, s5); o.w = pack2(s6, s7);
    } else {
        u32x4 told = reinterpret_cast<const u32x4*>(Told)[base];
        o.x = pack2(2.f * s0 - blo(told.x), 2.f * s1 - bhi(told.x));
        o.y = pack2(2.f * s2 - blo(told.y), 2.f * s3 - bhi(told.y));
        o.z = pack2(2.f * s4 - blo(told.z), 2.f * s5 - bhi(told.z));
        o.w = pack2(2.f * s6 - blo(told.w), 2.f * s7 - bhi(told.w));
    }
    reinterpret_cast<u32x4*>(Tout)[base] = o;
}

// ---- fallback (R4): unsorted 4-lane/node gather step ----
template<int NB, bool INIT>
__global__ __launch_bounds__(256, 4) void cheb_step4(
    const ushort* __restrict__ Tprev,
    const ushort* __restrict__ Told,
    ushort*       __restrict__ Tout,
    const int*    __restrict__ idx,
    const float*  __restrict__ wnb)
{
    int t = blockIdx.x * 256 + threadIdx.x;
    int n = t >> 2;
    int h = t & 3;

    const i32x4* ip = reinterpret_cast<const i32x4*>(idx + (size_t)n * NB);
    const f32x4* wv = reinterpret_cast<const f32x4*>(wnb + (size_t)n * NB);
    i32x4 I[NB / 4];
    f32x4 W[NB / 4];
#pragma unroll
    for (int j = 0; j < NB / 4; ++j) { I[j] = ip[j]; W[j] = wv[j]; }

    const u32x4* Tp = reinterpret_cast<const u32x4*>(Tprev);
    float s0 = 0.f, s1 = 0.f, s2 = 0.f, s3 = 0.f;
    float s4 = 0.f, s5 = 0.f, s6 = 0.f, s7 = 0.f;

#pragma unroll
    for (int j = 0; j < NB / 4; ++j) {
        i32x4 i4 = I[j]; f32x4 w4 = W[j];
#pragma unroll
        for (int e = 0; e < 4; ++e) {
            int   ii = (e == 0) ? i4.x : (e == 1) ? i4.y : (e == 2) ? i4.z : i4.w;
            float ww = (e == 0) ? w4.x : (e == 1) ? w4.y : (e == 2) ? w4.z : w4.w;
            u32x4 u = Tp[(size_t)ii * 4 + h];
            s0 += ww * blo(u.x); s1 += ww * bhi(u.x);
            s2 += ww * blo(u.y); s3 += ww * bhi(u.y);
            s4 += ww * blo(u.z); s5 += ww * bhi(u.z);
            s6 += ww * blo(u.w); s7 += ww * bhi(u.w);
        }
    }

    size_t base = (size_t)n * 4 + h;
    u32x4 o;
    if (INIT) {
        o.x = pack2(s0, s1); o.y = pack2(s2, s3);
        o.z = pack2(s4, s5); o.w = pack2(s6, s7);
    } else {
        u32x4 told = reinterpret_cast<const u32x4*>(Told)[base];
        o.x = pack2(2.f * s0 - blo(told.x), 2.f * s1 - bhi(told.x));
        o.y = pack2(2.f * s2 - blo(told.y), 2.f * s3 - bhi(told.y));
        o.z = pack2(2.f * s4 - blo(told.z), 2.f * s5 - bhi(told.z));
        o.w = pack2(2.f * s6 - blo(told.w), 2.f * s7 - bhi(told.w));
    }
    reinterpret_cast<u32x4*>(Tout)[base] = o;
}

// ----- finish: out = LN(relu([N,K*32] @ W2 + b)) (+resid), W2 built in-block -----
template<int K, bool RESIDUAL, bool OUT_BF16>
__global__ __launch_bounds__(256, 4) void finish_gemm(
    const ushort* __restrict__ chain,
    const float*  __restrict__ wd,     // [K][32][2]
    const float*  __restrict__ wp,     // [64][32]
    const float*  __restrict__ bias,
    const float*  __restrict__ gamma,
    const float*  __restrict__ beta,
    const float*  __restrict__ resid,
    void*         __restrict__ outp)
{
    constexpr int KW = K * 32;
    constexpr int WSTRIDE = KW + 8;
    __shared__ float swp[64 * 33];
    __shared__ __align__(16) ushort sW[32][WSTRIDE];

    int tid = threadIdx.x;
    int wv = tid >> 6, l = tid & 63;
    int r = l & 15, hi = l >> 4;
    int nbase = blockIdx.x * 64 + wv * 16;

    bf16x8 aF[K];
#pragma unroll
    for (int k = 0; k < K; ++k)
        aF[k] = *reinterpret_cast<const bf16x8*>(
            chain + (size_t)k * SLOT + (size_t)(nbase + r) * FF + hi * 8);

    for (int i = tid; i < 64 * 32; i += 256) {
        int u = i >> 5, g = i & 31;
        swp[u * 33 + g] = wp[i];
    }
    __syncthreads();

    for (int i = tid; i < 32 * KW; i += 256) {
        int g = i / KW, kf = i - g * KW;
        int f = kf & 31;
        float2 wdv = *reinterpret_cast<const float2*>(wd + (size_t)kf * 2);
        float w2 = wdv.x * swp[(2 * f) * 33 + g] + wdv.y * swp[(2 * f + 1) * 33 + g];
        sW[g][kf] = f2b(w2);
    }
    __syncthreads();

    f32x4 acc0 = {0.f, 0.f, 0.f, 0.f};
    f32x4 acc1 = {0.f, 0.f, 0.f, 0.f};
#pragma unroll
    for (int k = 0; k < K; ++k) {
        bf16x8 b0 = *reinterpret_cast<const bf16x8*>(&sW[r][k * 32 + hi * 8]);
        bf16x8 b1 = *reinterpret_cast<const bf16x8*>(&sW[16 + r][k * 32 + hi * 8]);
        acc0 = __builtin_amdgcn_mfma_f32_16x16x32_bf16(aF[k], b0, acc0, 0, 0, 0);
        acc1 = __builtin_amdgcn_mfma_f32_16x16x32_bf16(aF[k], b1, acc1, 0, 0, 0);
    }

    float bias_lo = bias[r],  bias_hi = bias[16 + r];
    float gam_lo  = gamma[r], gam_hi  = gamma[16 + r];
    float bet_lo  = beta[r],  bet_hi  = beta[16 + r];

#pragma unroll
    for (int v = 0; v < 4; ++v) {
        acc0[v] = fmaxf(acc0[v] + bias_lo, 0.f);
        acc1[v] = fmaxf(acc1[v] + bias_hi, 0.f);
    }
#pragma unroll
    for (int v = 0; v < 4; ++v) {
        float s1 = acc0[v] + acc1[v];
        float s2 = acc0[v] * acc0[v] + acc1[v] * acc1[v];
#pragma unroll
        for (int m = 1; m < 16; m <<= 1) {
            s1 += __shfl_xor(s1, m);
            s2 += __shfl_xor(s2, m);
        }
        float mu  = s1 * (1.f / 32.f);
        float var = s2 * (1.f / 32.f) - mu * mu;
        float rs  = rsqrtf(var + 1e-6f);
        int n = nbase + hi * 4 + v;
        size_t o0 = (size_t)n * FF + r;
        size_t o1 = o0 + 16;
        float z0 = (acc0[v] - mu) * rs * gam_lo + bet_lo;
        float z1 = (acc1[v] - mu) * rs * gam_hi + bet_hi;
        if (RESIDUAL) { z0 += resid[o0]; z1 += resid[o1]; }
        if (OUT_BF16) {
            ((ushort*)outp)[o0] = f2b(z0);
            ((ushort*)outp)[o1] = f2b(z1);
        } else {
            ((float*)outp)[o0] = z0;
            ((float*)outp)[o1] = z1;
        }
    }
}

extern "C" void kernel_launch(void* const* d_in, const int* in_sizes, int n_in,
                              void* d_out, int out_size, void* d_ws, size_t ws_size,
                              hipStream_t stream) {
    const float* maps = (const float*)d_in[0];
    const int*   idx1 = (const int*)  d_in[1];
    const float* w1nb = (const float*)d_in[2];
    const int*   idx2 = (const int*)  d_in[3];
    const float* w2nb = (const float*)d_in[4];
    const float* wd1  = (const float*)d_in[5];
    const float* wp1  = (const float*)d_in[6];
    const float* b1   = (const float*)d_in[7];
    const float* g1   = (const float*)d_in[8];
    const float* be1  = (const float*)d_in[9];
    const float* wd2  = (const float*)d_in[10];
    const float* wp2  = (const float*)d_in[11];
    const float* b2   = (const float*)d_in[12];
    const float* g2   = (const float*)d_in[13];
    const float* be2  = (const float*)d_in[14];
    float* out = (float*)d_out;

    // ws: 10 bf16 chain slots (125.8 MB) + padded layer-2 slots (50.3 MB).
    // edges1 (12.6 MB) aliases slot B1 (dead until layer-2 init overwrites it).
    ushort* slots = (ushort*)d_ws;
    ushort* B = slots;
    ushort* A = slots + 4 * SLOT;
    ulong* edges1  = (ulong*)(B + SLOT);                 // aliases B1 region
    ulong* edgesP2 = (ulong*)(slots + 10 * SLOT);        // [N*32]

    const size_t needFull = 10 * SLOT * 2 + (size_t)NPIX * 32 * 8;
    const bool useSorted = ws_size >= needFull;

    const int stepBlocks = NPIX * 4 / 256;        // 3072
    const int cvtBlocks  = NPIX * FF / (256 * 4); // 6144
    const int finBlocks  = NPIX / 64;             // 3072
    const int sortBlocks = NPIX / 256;            // 768

    if (useSorted) {
        sort_edges<8><<<sortBlocks, 256, 0, stream>>>(idx1, w1nb, edges1);
        build_slots<20, 32><<<sortBlocks, 256, 0, stream>>>(idx2, w2nb, edgesP2);

        // ---------------- layer 1: K=6, NB=8 ----------------
        f2b_kernel<<<cvtBlocks, 256, 0, stream>>>(maps, A);   // A0
        cheb_stepC<8, 2, true><<<stepBlocks, 256, 0, stream>>>(A, nullptr, A + SLOT, edges1);
        cheb_stepC<8, 2, false><<<stepBlocks, 256, 0, stream>>>(A + SLOT,     A,            A + 2 * SLOT, edges1);
        cheb_stepC<8, 2, false><<<stepBlocks, 256, 0, stream>>>(A + 2 * SLOT, A + SLOT,     A + 3 * SLOT, edges1);
        cheb_stepC<8, 2, false><<<stepBlocks, 256, 0, stream>>>(A + 3 * SLOT, A + 2 * SLOT, A + 4 * SLOT, edges1);
        cheb_stepC<8, 2, false><<<stepBlocks, 256, 0, stream>>>(A + 4 * SLOT, A + 3 * SLOT, A + 5 * SLOT, edges1);
        finish_gemm<6, false, true><<<finBlocks, 256, 0, stream>>>(A, wd1, wp1, b1, g1, be1, nullptr, B);

        // ---------------- layer 2: K=10, NB=20 (padded slots) ----------------
        cheb_stepP<32, true><<<stepBlocks, 256, 0, stream>>>(B, nullptr, B + SLOT, edgesP2);
        for (int k = 2; k <= 9; ++k)
            cheb_stepP<32, false><<<stepBlocks, 256, 0, stream>>>(
                B + (size_t)(k - 1) * SLOT, B + (size_t)(k - 2) * SLOT,
                B + (size_t)k * SLOT, edgesP2);
    } else {
        // ---------------- fallback: R4 path ----------------
        f2b_kernel<<<cvtBlocks, 256, 0, stream>>>(maps, A);
        cheb_step4<8, true><<<stepBlocks, 256, 0, stream>>>(A, nullptr, A + SLOT, idx1, w1nb);
        cheb_step4<8, false><<<stepBlocks, 256, 0, stream>>>(A + SLOT,     A,            A + 2 * SLOT, idx1, w1nb);
        cheb_step4<8, false><<<stepBlocks, 256, 0, stream>>>(A + 2 * SLOT, A + SLOT,     A + 3 * SLOT, idx1, w1nb);
        cheb_step4<8, false><<<stepBlocks, 256, 0, stream>>>(A + 3 * SLOT, A + 2 * SLOT, A + 4 * SLOT, idx1, w1nb);
        cheb_step4<8, false><<<stepBlocks, 256, 0, stream>>>(A + 4 * SLOT, A + 3 * SLOT, A + 5 * SLOT, idx1, w1nb);
        finish_gemm<6, false, true><<<finBlocks, 256, 0, stream>>>(A, wd1, wp1, b1, g1, be1, nullptr, B);
        cheb_step4<20, true><<<stepBlocks, 256, 0, stream>>>(B, nullptr, B + SLOT, idx2, w2nb);
        for (int k = 2; k <= 9; ++k)
            cheb_step4<20, false><<<stepBlocks, 256, 0, stream>>>(
                B + (size_t)(k - 1) * SLOT, B + (size_t)(k - 2) * SLOT,
                B + (size_t)k * SLOT, idx2, w2nb);
    }
    finish_gemm<10, true, false><<<finBlocks, 256, 0, stream>>>(B, wd2, wp2, b2, g2, be2, maps, out);
}

// Round 10
// 788.043 us; speedup vs baseline: 1.8573x; 1.8573x over previous
//
#include <hip/hip_runtime.h>

constexpr int NPIX = 196608;
constexpr int FF   = 32;
constexpr size_t SLOT = (size_t)NPIX * FF;

typedef short bf16x8 __attribute__((ext_vector_type(8)));
typedef float f32x4  __attribute__((ext_vector_type(4)));
typedef int   i32x4  __attribute__((ext_vector_type(4)));
typedef uint  u32x4  __attribute__((ext_vector_type(4)));

__device__ __forceinline__ float blo(uint u) {
    union { float f; uint i; } v; v.i = u << 16; return v.f;
}
__device__ __forceinline__ float bhi(uint u) {
    union { float f; uint i; } v; v.i = u & 0xffff0000u; return v.f;
}
__device__ __forceinline__ ushort f2b(float f) {
    union { float f; uint i; } v; v.f = f;
    uint r = v.i + 0x7fffu + ((v.i >> 16) & 1u);   // RNE
    return (ushort)(r >> 16);
}
__device__ __forceinline__ uint pack2(float lo, float hi) {
    return ((uint)f2b(hi) << 16) | (uint)f2b(lo);
}
__device__ __forceinline__ float wbits(ulong e) {
    union { float f; uint u; } v; v.u = (uint)e; return v.f;
}

// ---------------- fp32 -> bf16 convert (maps -> chain T0) ----------------
__global__ __launch_bounds__(256) void f2b_kernel(const float* __restrict__ src,
                                                  ushort* __restrict__ dst) {
    int i = (blockIdx.x * 256 + threadIdx.x) * 4;
    f32x4 v = *reinterpret_cast<const f32x4*>(src + i);
    ushort4 o;
    o.x = f2b(v.x); o.y = f2b(v.y); o.z = f2b(v.z); o.w = f2b(v.w);
    *reinterpret_cast<ushort4*>(dst + i) = o;
}

// ---- one-time: pack (idx,w) into ulong and sort each node's edges by src ----
template<int NB>
__global__ __launch_bounds__(256) void sort_edges(
    const int*   __restrict__ idx,
    const float* __restrict__ wnb,
    ulong*       __restrict__ edges)
{
    int n = blockIdx.x * 256 + threadIdx.x;
    ulong a[NB];
#pragma unroll
    for (int j = 0; j < NB; ++j) {
        union { float f; uint u; } w; w.f = wnb[(size_t)n * NB + j];
        a[j] = ((ulong)(uint)idx[(size_t)n * NB + j] << 32) | (ulong)w.u;
    }
#pragma unroll
    for (int r = 0; r < NB; ++r) {
#pragma unroll
        for (int i = (r & 1); i + 1 < NB; i += 2) {
            if (a[i] > a[i + 1]) { ulong t = a[i]; a[i] = a[i + 1]; a[i + 1] = t; }
        }
    }
#pragma unroll
    for (int j = 0; j < NB; ++j)
        edges[(size_t)n * NB + j] = a[j];
}

// ---- pipelined chunked sorted sweep ----
// Chunks of 4 edges in ascending-src order. Software pipeline (all scalar named
// regs, no arrays -> no scratch): edges fetched 2 chunks ahead, gathers issued
// 1 chunk ahead, FMAs on current chunk; sched_barrier(0) pins the temporal
// sweep so co-resident waves share each quantile window in per-XCD L2.
// INIT: Tout = L(Tprev). else: Tout = 2 L(Tprev) - Told.
template<int NB, int NCH, bool INIT>
__global__ __launch_bounds__(256, 4) void cheb_stepC2(
    const ushort* __restrict__ Tprev,
    const ushort* __restrict__ Told,
    ushort*       __restrict__ Tout,
    const ulong*  __restrict__ edges)
{
    static_assert(NB == NCH * 4, "chunk size must be 4");
    int t = blockIdx.x * 256 + threadIdx.x;
    int n = t >> 2;          // node
    int h = t & 3;           // feature octet

    const ulong* ep = edges + (size_t)n * NB;
    const u32x4* Tp = reinterpret_cast<const u32x4*>(Tprev);

    // prologue: edges chunk0 -> gathers chunk0; edges chunk1
    ulong Ea0 = ep[0], Ea1 = ep[1], Ea2 = ep[2], Ea3 = ep[3];
    u32x4 u0 = Tp[(size_t)(uint)(Ea0 >> 32) * 4 + h];
    u32x4 u1 = Tp[(size_t)(uint)(Ea1 >> 32) * 4 + h];
    u32x4 u2 = Tp[(size_t)(uint)(Ea2 >> 32) * 4 + h];
    u32x4 u3 = Tp[(size_t)(uint)(Ea3 >> 32) * 4 + h];
    ulong Eb0 = 0, Eb1 = 0, Eb2 = 0, Eb3 = 0;
    if (NCH > 1) { Eb0 = ep[4]; Eb1 = ep[5]; Eb2 = ep[6]; Eb3 = ep[7]; }

    float s0 = 0.f, s1 = 0.f, s2 = 0.f, s3 = 0.f;
    float s4 = 0.f, s5 = 0.f, s6 = 0.f, s7 = 0.f;

#pragma unroll
    for (int c = 0; c < NCH; ++c) {
        u32x4 v0, v1, v2, v3;
        ulong En0 = 0, En1 = 0, En2 = 0, En3 = 0;
        if (c + 1 < NCH) {           // issue next chunk's gathers (independent)
            v0 = Tp[(size_t)(uint)(Eb0 >> 32) * 4 + h];
            v1 = Tp[(size_t)(uint)(Eb1 >> 32) * 4 + h];
            v2 = Tp[(size_t)(uint)(Eb2 >> 32) * 4 + h];
            v3 = Tp[(size_t)(uint)(Eb3 >> 32) * 4 + h];
        }
        if (c + 2 < NCH) {           // fetch edges two chunks ahead
            En0 = ep[(c + 2) * 4 + 0];
            En1 = ep[(c + 2) * 4 + 1];
            En2 = ep[(c + 2) * 4 + 2];
            En3 = ep[(c + 2) * 4 + 3];
        }
        float w0 = wbits(Ea0), w1 = wbits(Ea1), w2 = wbits(Ea2), w3 = wbits(Ea3);
        s0 += w0 * blo(u0.x); s1 += w0 * bhi(u0.x);
        s2 += w0 * blo(u0.y); s3 += w0 * bhi(u0.y);
        s4 += w0 * blo(u0.z); s5 += w0 * bhi(u0.z);
        s6 += w0 * blo(u0.w); s7 += w0 * bhi(u0.w);
        s0 += w1 * blo(u1.x); s1 += w1 * bhi(u1.x);
        s2 += w1 * blo(u1.y); s3 += w1 * bhi(u1.y);
        s4 += w1 * blo(u1.z); s5 += w1 * bhi(u1.z);
        s6 += w1 * blo(u1.w); s7 += w1 * bhi(u1.w);
        s0 += w2 * blo(u2.x); s1 += w2 * bhi(u2.x);
        s2 += w2 * blo(u2.y); s3 += w2 * bhi(u2.y);
        s4 += w2 * blo(u2.z); s5 += w2 * bhi(u2.z);
        s6 += w2 * blo(u2.w); s7 += w2 * bhi(u2.w);
        s0 += w3 * blo(u3.x); s1 += w3 * bhi(u3.x);
        s2 += w3 * blo(u3.y); s3 += w3 * bhi(u3.y);
        s4 += w3 * blo(u3.z); s5 += w3 * bhi(u3.z);
        s6 += w3 * blo(u3.w); s7 += w3 * bhi(u3.w);
        __builtin_amdgcn_sched_barrier(0);   // pin temporal sweep order
        if (c + 1 < NCH) {
            u0 = v0; u1 = v1; u2 = v2; u3 = v3;
            Ea0 = Eb0; Ea1 = Eb1; Ea2 = Eb2; Ea3 = Eb3;
        }
        if (c + 2 < NCH) { Eb0 = En0; Eb1 = En1; Eb2 = En2; Eb3 = En3; }
    }

    size_t base = (size_t)n * 4 + h;
    u32x4 o;
    if (INIT) {
        o.x = pack2(s0, s1); o.y = pack2(s2, s3);
        o.z = pack2(s4, s5); o.w = pack2(s6, s7);
    } else {
        u32x4 told = reinterpret_cast<const u32x4*>(Told)[base];
        o.x = pack2(2.f * s0 - blo(told.x), 2.f * s1 - bhi(told.x));
        o.y = pack2(2.f * s2 - blo(told.y), 2.f * s3 - bhi(told.y));
        o.z = pack2(2.f * s4 - blo(told.z), 2.f * s5 - bhi(told.z));
        o.w = pack2(2.f * s6 - blo(told.w), 2.f * s7 - bhi(told.w));
    }
    reinterpret_cast<u32x4*>(Tout)[base] = o;
}

// ---- fallback (R4): unsorted 4-lane/node gather step ----
template<int NB, bool INIT>
__global__ __launch_bounds__(256, 4) void cheb_step4(
    const ushort* __restrict__ Tprev,
    const ushort* __restrict__ Told,
    ushort*       __restrict__ Tout,
    const int*    __restrict__ idx,
    const float*  __restrict__ wnb)
{
    int t = blockIdx.x * 256 + threadIdx.x;
    int n = t >> 2;
    int h = t & 3;

    const i32x4* ip = reinterpret_cast<const i32x4*>(idx + (size_t)n * NB);
    const f32x4* wv = reinterpret_cast<const f32x4*>(wnb + (size_t)n * NB);
    i32x4 I[NB / 4];
    f32x4 W[NB / 4];
#pragma unroll
    for (int j = 0; j < NB / 4; ++j) { I[j] = ip[j]; W[j] = wv[j]; }

    const u32x4* Tp = reinterpret_cast<const u32x4*>(Tprev);
    float s0 = 0.f, s1 = 0.f, s2 = 0.f, s3 = 0.f;
    float s4 = 0.f, s5 = 0.f, s6 = 0.f, s7 = 0.f;

#pragma unroll
    for (int j = 0; j < NB / 4; ++j) {
        i32x4 i4 = I[j]; f32x4 w4 = W[j];
#pragma unroll
        for (int e = 0; e < 4; ++e) {
            int   ii = (e == 0) ? i4.x : (e == 1) ? i4.y : (e == 2) ? i4.z : i4.w;
            float ww = (e == 0) ? w4.x : (e == 1) ? w4.y : (e == 2) ? w4.z : w4.w;
            u32x4 u = Tp[(size_t)ii * 4 + h];
            s0 += ww * blo(u.x); s1 += ww * bhi(u.x);
            s2 += ww * blo(u.y); s3 += ww * bhi(u.y);
            s4 += ww * blo(u.z); s5 += ww * bhi(u.z);
            s6 += ww * blo(u.w); s7 += ww * bhi(u.w);
        }
    }

    size_t base = (size_t)n * 4 + h;
    u32x4 o;
    if (INIT) {
        o.x = pack2(s0, s1); o.y = pack2(s2, s3);
        o.z = pack2(s4, s5); o.w = pack2(s6, s7);
    } else {
        u32x4 told = reinterpret_cast<const u32x4*>(Told)[base];
        o.x = pack2(2.f * s0 - blo(told.x), 2.f * s1 - bhi(told.x));
        o.y = pack2(2.f * s2 - blo(told.y), 2.f * s3 - bhi(told.y));
        o.z = pack2(2.f * s4 - blo(told.z), 2.f * s5 - bhi(told.z));
        o.w = pack2(2.f * s6 - blo(told.w), 2.f * s7 - bhi(told.w));
    }
    reinterpret_cast<u32x4*>(Tout)[base] = o;
}

// ----- finish: out = LN(relu([N,K*32] @ W2 + b)) (+resid), W2 built in-block -----
template<int K, bool RESIDUAL, bool OUT_BF16>
__global__ __launch_bounds__(256, 4) void finish_gemm(
    const ushort* __restrict__ chain,
    const float*  __restrict__ wd,     // [K][32][2]
    const float*  __restrict__ wp,     // [64][32]
    const float*  __restrict__ bias,
    const float*  __restrict__ gamma,
    const float*  __restrict__ beta,
    const float*  __restrict__ resid,
    void*         __restrict__ outp)
{
    constexpr int KW = K * 32;
    constexpr int WSTRIDE = KW + 8;
    __shared__ float swp[64 * 33];
    __shared__ __align__(16) ushort sW[32][WSTRIDE];

    int tid = threadIdx.x;
    int wv = tid >> 6, l = tid & 63;
    int r = l & 15, hi = l >> 4;
    int nbase = blockIdx.x * 64 + wv * 16;

    bf16x8 aF[K];
#pragma unroll
    for (int k = 0; k < K; ++k)
        aF[k] = *reinterpret_cast<const bf16x8*>(
            chain + (size_t)k * SLOT + (size_t)(nbase + r) * FF + hi * 8);

    for (int i = tid; i < 64 * 32; i += 256) {
        int u = i >> 5, g = i & 31;
        swp[u * 33 + g] = wp[i];
    }
    __syncthreads();

    for (int i = tid; i < 32 * KW; i += 256) {
        int g = i / KW, kf = i - g * KW;
        int f = kf & 31;
        float2 wdv = *reinterpret_cast<const float2*>(wd + (size_t)kf * 2);
        float w2 = wdv.x * swp[(2 * f) * 33 + g] + wdv.y * swp[(2 * f + 1) * 33 + g];
        sW[g][kf] = f2b(w2);
    }
    __syncthreads();

    f32x4 acc0 = {0.f, 0.f, 0.f, 0.f};
    f32x4 acc1 = {0.f, 0.f, 0.f, 0.f};
#pragma unroll
    for (int k = 0; k < K; ++k) {
        bf16x8 b0 = *reinterpret_cast<const bf16x8*>(&sW[r][k * 32 + hi * 8]);
        bf16x8 b1 = *reinterpret_cast<const bf16x8*>(&sW[16 + r][k * 32 + hi * 8]);
        acc0 = __builtin_amdgcn_mfma_f32_16x16x32_bf16(aF[k], b0, acc0, 0, 0, 0);
        acc1 = __builtin_amdgcn_mfma_f32_16x16x32_bf16(aF[k], b1, acc1, 0, 0, 0);
    }

    float bias_lo = bias[r],  bias_hi = bias[16 + r];
    float gam_lo  = gamma[r], gam_hi  = gamma[16 + r];
    float bet_lo  = beta[r],  bet_hi  = beta[16 + r];

#pragma unroll
    for (int v = 0; v < 4; ++v) {
        acc0[v] = fmaxf(acc0[v] + bias_lo, 0.f);
        acc1[v] = fmaxf(acc1[v] + bias_hi, 0.f);
    }
#pragma unroll
    for (int v = 0; v < 4; ++v) {
        float s1 = acc0[v] + acc1[v];
        float s2 = acc0[v] * acc0[v] + acc1[v] * acc1[v];
#pragma unroll
        for (int m = 1; m < 16; m <<= 1) {
            s1 += __shfl_xor(s1, m);
            s2 += __shfl_xor(s2, m);
        }
        float mu  = s1 * (1.f / 32.f);
        float var = s2 * (1.f / 32.f) - mu * mu;
        float rs  = rsqrtf(var + 1e-6f);
        int n = nbase + hi * 4 + v;
        size_t o0 = (size_t)n * FF + r;
        size_t o1 = o0 + 16;
        float z0 = (acc0[v] - mu) * rs * gam_lo + bet_lo;
        float z1 = (acc1[v] - mu) * rs * gam_hi + bet_hi;
        if (RESIDUAL) { z0 += resid[o0]; z1 += resid[o1]; }
        if (OUT_BF16) {
            ((ushort*)outp)[o0] = f2b(z0);
            ((ushort*)outp)[o1] = f2b(z1);
        } else {
            ((float*)outp)[o0] = z0;
            ((float*)outp)[o1] = z1;
        }
    }
}

extern "C" void kernel_launch(void* const* d_in, const int* in_sizes, int n_in,
                              void* d_out, int out_size, void* d_ws, size_t ws_size,
                              hipStream_t stream) {
    const float* maps = (const float*)d_in[0];
    const int*   idx1 = (const int*)  d_in[1];
    const float* w1nb = (const float*)d_in[2];
    const int*   idx2 = (const int*)  d_in[3];
    const float* w2nb = (const float*)d_in[4];
    const float* wd1  = (const float*)d_in[5];
    const float* wp1  = (const float*)d_in[6];
    const float* b1   = (const float*)d_in[7];
    const float* g1   = (const float*)d_in[8];
    const float* be1  = (const float*)d_in[9];
    const float* wd2  = (const float*)d_in[10];
    const float* wp2  = (const float*)d_in[11];
    const float* b2   = (const float*)d_in[12];
    const float* g2   = (const float*)d_in[13];
    const float* be2  = (const float*)d_in[14];
    float* out = (float*)d_out;

    // ws: 10 bf16 chain slots (125.8 MB) + sorted edge arrays (44 MB)
    ushort* slots = (ushort*)d_ws;
    ushort* B = slots;
    ushort* A = slots + 4 * SLOT;
    ulong* edges2 = (ulong*)(slots + 10 * SLOT);            // [N*20]
    ulong* edges1 = edges2 + (size_t)NPIX * 20;             // [N*8]

    const size_t needSorted = 10 * SLOT * 2 + (size_t)NPIX * 20 * 8 + (size_t)NPIX * 8 * 8;
    const bool useSorted = ws_size >= needSorted;

    const int stepBlocks = NPIX * 4 / 256;        // 3072
    const int cvtBlocks  = NPIX * FF / (256 * 4); // 6144
    const int finBlocks  = NPIX / 64;             // 3072
    const int sortBlocks = NPIX / 256;            // 768

    if (useSorted) {
        sort_edges<8><<<sortBlocks, 256, 0, stream>>>(idx1, w1nb, edges1);
        sort_edges<20><<<sortBlocks, 256, 0, stream>>>(idx2, w2nb, edges2);
    }

    // ---------------- layer 1: K=6, NB=8 ----------------
    f2b_kernel<<<cvtBlocks, 256, 0, stream>>>(maps, A);   // A0
    if (useSorted) {
        cheb_stepC2<8, 2, true><<<stepBlocks, 256, 0, stream>>>(A, nullptr, A + SLOT, edges1);
        cheb_stepC2<8, 2, false><<<stepBlocks, 256, 0, stream>>>(A + SLOT,     A,            A + 2 * SLOT, edges1);
        cheb_stepC2<8, 2, false><<<stepBlocks, 256, 0, stream>>>(A + 2 * SLOT, A + SLOT,     A + 3 * SLOT, edges1);
        cheb_stepC2<8, 2, false><<<stepBlocks, 256, 0, stream>>>(A + 3 * SLOT, A + 2 * SLOT, A + 4 * SLOT, edges1);
        cheb_stepC2<8, 2, false><<<stepBlocks, 256, 0, stream>>>(A + 4 * SLOT, A + 3 * SLOT, A + 5 * SLOT, edges1);
    } else {
        cheb_step4<8, true><<<stepBlocks, 256, 0, stream>>>(A, nullptr, A + SLOT, idx1, w1nb);
        cheb_step4<8, false><<<stepBlocks, 256, 0, stream>>>(A + SLOT,     A,            A + 2 * SLOT, idx1, w1nb);
        cheb_step4<8, false><<<stepBlocks, 256, 0, stream>>>(A + 2 * SLOT, A + SLOT,     A + 3 * SLOT, idx1, w1nb);
        cheb_step4<8, false><<<stepBlocks, 256, 0, stream>>>(A + 3 * SLOT, A + 2 * SLOT, A + 4 * SLOT, idx1, w1nb);
        cheb_step4<8, false><<<stepBlocks, 256, 0, stream>>>(A + 4 * SLOT, A + 3 * SLOT, A + 5 * SLOT, idx1, w1nb);
    }
    finish_gemm<6, false, true><<<finBlocks, 256, 0, stream>>>(A, wd1, wp1, b1, g1, be1, nullptr, B);  // -> B0

    // ---------------- layer 2: K=10, NB=20 ----------------
    if (useSorted) {
        cheb_stepC2<20, 5, true><<<stepBlocks, 256, 0, stream>>>(B, nullptr, B + SLOT, edges2);
        for (int k = 2; k <= 9; ++k)
            cheb_stepC2<20, 5, false><<<stepBlocks, 256, 0, stream>>>(
                B + (size_t)(k - 1) * SLOT, B + (size_t)(k - 2) * SLOT,
                B + (size_t)k * SLOT, edges2);
    } else {
        cheb_step4<20, true><<<stepBlocks, 256, 0, stream>>>(B, nullptr, B + SLOT, idx2, w2nb);
        for (int k = 2; k <= 9; ++k)
            cheb_step4<20, false><<<stepBlocks, 256, 0, stream>>>(
                B + (size_t)(k - 1) * SLOT, B + (size_t)(k - 2) * SLOT,
                B + (size_t)k * SLOT, idx2, w2nb);
    }
    finish_gemm<10, true, false><<<finBlocks, 256, 0, stream>>>(B, wd2, wp2, b2, g2, be2, maps, out);
}